// Round 5
// baseline (2593.340 us; speedup 1.0000x reference)
//
#include <hip/hip_runtime.h>
#include <hip/hip_bf16.h>

typedef __bf16 bf16x8 __attribute__((ext_vector_type(8)));
typedef float f32x4 __attribute__((ext_vector_type(4)));
typedef unsigned int u32x4 __attribute__((ext_vector_type(4)));

#define BB   128
#define SS   512
#define DD   128
#define HH   1024
#define OO   64
#define IIN  257

// 8 batch groups (16 rows) x 64 blocks; block owns 16 h-cols (64 gate cols).
// 4 waves = 4 K-quarters, W_hh B-frags persistent in VGPRs.
// Round-3 result: XCD co-location (p = bid&7) cut FETCH 702->164 MB but not
// time — sc1 always pays MALL RTT. This round: runtime-PROVEN intra-XCD FAST
// mode. (1) id check via s_getreg(HW_REG_XCC_ID): all 64 blocks of the group
// on one XCD. (2) sc0 RENDEZVOUS: bounded-spin proof that sc0-store ->
// sc0-load through the shared per-XCD L2 actually works, refereed over the
// always-correct sc1 channel (write-once values, unconditional publishes ->
// deadlock-free). FAST only on unanimous ok; else SAFE = round-3 sc1 protocol
// bit-exact. Placement stays a performance heuristic; correctness never
// depends on it (G16).
#define NGROUP 8
#define GBLK   64
#define MG     16
#define KK_H   32     // 1024/32 ksteps
#define KK_X   9      // 288/32

#define XTP_TP    (KK_X*512)      // 4608 bf16 per (t,p)
#define HBUF_SLAB (KK_H*512)      // 16384 bf16 = 32 KB per (p,buf)
#define WIH_BLK   (4*KK_X*512)    // 18432 bf16 per q

// ws layout (bytes): flags 8K | hbuf 512K | hlast 512K | xtp 36M | wihp 2.25M
// (unchanged from round 3 — no ws_size risk). The id/marker/outcome arrays
// (6 KB) overlap the FIRST 24 KB of hlast: they are only used in the
// prologue, and hlast is only written at t=SS-1, which every block reaches
// strictly after every block's prologue (step-t poll needs all flags >= t).
#define WS_HBUF  8192
#define WS_HLAST 532480
#define WS_XTP   1056768
#define WS_WIHP  38805504

// ---- cache-op helpers. sc1: bypass L1/L2, coherent at MALL (SAFE mode +
// referee channel). sc0 store: write-through to the shared per-XCD L2;
// sc0 load: L1-bypass, L2-served (FAST mode, same-XCD only, runtime-proven).
// NO agent-scope compiler fences anywhere: they emit buffer_inv/buffer_wbl2
// which nuke the L2-resident working set (measured: 10x regression, round 1).
__device__ __forceinline__ void stg_sc1(void* p, unsigned int v) {
  asm volatile("global_store_dword %0, %1, off sc1" :: "v"(p), "v"(v));
}
__device__ __forceinline__ void stg_sc0(void* p, unsigned int v) {
  asm volatile("global_store_dword %0, %1, off sc0" :: "v"(p), "v"(v));
}
__device__ __forceinline__ unsigned int poll_sc1(const unsigned int* p) {
  unsigned int f;
  asm volatile("global_load_dword %0, %1, off sc1\n\ts_waitcnt vmcnt(0)" : "=v"(f) : "v"(p));
  return f;
}
__device__ __forceinline__ unsigned int poll_sc0(const unsigned int* p) {
  unsigned int f;
  asm volatile("global_load_dword %0, %1, off sc0\n\ts_waitcnt vmcnt(0)" : "=v"(f) : "v"(p));
  return f;
}
template<bool FAST>
__device__ __forceinline__ u32x4 ldh16(const void* p) {
  u32x4 r;
  if (FAST) asm volatile("global_load_dwordx4 %0, %1, off sc0" : "=v"(r) : "v"(p));
  else      asm volatile("global_load_dwordx4 %0, %1, off sc1" : "=v"(r) : "v"(p));
  return r;
}
template<bool FAST>
__device__ __forceinline__ void sth4(void* p, unsigned int v) {
  if (FAST) stg_sc0(p, v); else stg_sc1(p, v);
}
template<bool FAST>
__device__ __forceinline__ unsigned int pollld(const unsigned int* p) {
  return FAST ? poll_sc0(p) : poll_sc1(p);
}
__device__ __forceinline__ bf16x8 asbf(u32x4 v) {
  union { u32x4 u; bf16x8 h; } c; c.u = v; return c.h;
}

#define CLAIMW4(CNTSTR, A, O)                                        \
  asm volatile("s_waitcnt vmcnt(" CNTSTR ")"                         \
    : "+v"((A)[(O)]), "+v"((A)[(O)+1]), "+v"((A)[(O)+2]), "+v"((A)[(O)+3]))

// Zero step-flags (2048 dwords) + prologue aux arrays (2048 dwords in the
// hlast region) with sc1 stores — MALL-coherent with all sc1 readers.
__global__ void flag_init(unsigned int* __restrict__ flags, unsigned int* __restrict__ aux) {
  int i = blockIdx.x * 256 + threadIdx.x;          // 4096
  if (i < 2048) stg_sc1(flags + i, 0u);
  else          stg_sc1(aux + (i - 2048), 0u);
}

// xtp A-frags (16x16x32 A: m=lane&15, k=kk*32+(lane>>4)*8+j):
// idx = ((t*8+p)*9 + kk)*512 + l*8 + j
__global__ void prepack_kernel(const float* __restrict__ x, const float* __restrict__ mask,
                               const float* __restrict__ ti, __bf16* __restrict__ xtp) {
  int idx = blockIdx.x * 256 + threadIdx.x;        // 18,874,368
  int j = idx & 7, l = (idx >> 3) & 63;
  int rest = idx >> 9;
  int kk = rest % 9;
  int rest2 = rest / 9;
  int p = rest2 & 7;
  int t = rest2 >> 3;
  int b = p * MG + (l & 15);
  int k = kk * 32 + ((l >> 4) << 3) + j;
  float v;
  if (k < 128)       v = x[(b * SS + t) * DD + k];
  else if (k < 256)  v = mask[(b * SS + t) * DD + (k - 128)];
  else if (k == 256) v = ti[b * SS + t];
  else               v = 0.f;
  xtp[idx] = (__bf16)v;
}

// W_ih B-frags per col-slice q: [q][nt][kk][lane][8], nt = gate
__global__ void wih_prepack(const float* __restrict__ W_ih, __bf16* __restrict__ wihp) {
  int idx = blockIdx.x * 256 + threadIdx.x;        // 1,179,648
  int j = idx & 7, l = (idx >> 3) & 63;
  int rest = idx >> 9;
  int kk = rest % 9;
  int rest2 = rest / 9;
  int nt = rest2 & 3, q = rest2 >> 2;
  int col = nt * HH + q * 16 + (l & 15);
  int k = kk * 32 + ((l >> 4) << 3) + j;
  wihp[idx] = (k < IIN) ? (__bf16)W_ih[col * IIN + k] : (__bf16)0.f;
}

__device__ __forceinline__ float sigmoid_f(float v) { return 1.f / (1.f + __expf(-v)); }
__device__ __forceinline__ float tanh_f(float v)    { return 1.f - 2.f / (__expf(2.f * v) + 1.f); }

// Step flags: value = t+1 (1..511). Poll at step t accepts (f - t) <= 1u
// (legit window {t-1,t,t+1} -> waits on t-1, accepts t/t+1); stale values
// can't appear (flag_init + write-once prologue regions + dispatch acquire).
template<bool FAST>
__device__ __forceinline__ void run_scan(
    int p, int q, int j0, int w, int l, int n16, int qh, int grow,
    unsigned int* gflags,
    const bf16x8 (&breg)[4][8], const float (&bias_r)[4],
    const __bf16* __restrict__ xtp, const __bf16* __restrict__ wihp,
    __bf16* __restrict__ hbuf, float* __restrict__ hlast, float* red_lds) {
  float creg = 0.f;
  // x-part K split over waves: kk in [xs, xe)
  const int xs = (w == 0) ? 0 : (2 * w + 1);
  const int xe = xs + ((w == 0) ? 3 : 2);

  for (int t = 0; t < SS; ++t) {
    const int rb = t & 1, wb = rb ^ 1;
    f32x4 acc[4];
    #pragma unroll
    for (int ntI = 0; ntI < 4; ++ntI) acc[ntI] = (f32x4){0.f, 0.f, 0.f, 0.f};

    // x-part (this wave's K-slice), pre-poll; A from xtp, B from wihp (cached)
    for (int kk = xs; kk < xe; ++kk) {
      const __bf16* xb = xtp + ((size_t)(t * 8 + p) * KK_X + kk) * 512 + l * 8;
      bf16x8 a = *(const bf16x8*)xb;
      #pragma unroll
      for (int ntI = 0; ntI < 4; ++ntI) {
        bf16x8 b = *(const bf16x8*)(wihp + ((size_t)(q * 4 + ntI) * KK_X + kk) * 512 + l * 8);
        acc[ntI] = __builtin_amdgcn_mfma_f32_16x16x32_bf16(a, b, acc[ntI], 0, 0, 0);
      }
    }

    // per-wave poll: wave w consumes blocks q' in [16w,16w+16) == flags
    // gflags[64w + lane]. Union over the 4 waves covers all 256 flags before
    // the deposit barrier -> slab WAR-safety unchanged. t==0: h0==0 -> skip
    // h-part (hbuf never read before a flag-protected write; no hbuf init).
    if (t > 0) {
      {
        const unsigned int tgt = (unsigned int)t;
        const unsigned int* fp = gflags + (w << 6) + l;
        for (;;) {
          unsigned int f = pollld<FAST>(fp);
          if (!__ballot((f - tgt) > 1u)) break;
          __builtin_amdgcn_s_sleep(1);
        }
        __builtin_amdgcn_sched_barrier(0);
      }

      // h-part: this wave's K-quarter (8 ksteps). A via mode path, B VGPRs.
      const __bf16* hbL = hbuf + (p * 2 + rb) * HBUF_SLAB + (w * 8) * 512 + l * 8;
      u32x4 A[8];
      #pragma unroll
      for (int i = 0; i < 8; ++i) A[i] = ldh16<FAST>(hbL + i * 512);

      CLAIMW4("4", A, 0);
      #pragma unroll
      for (int i = 0; i < 4; ++i)
        #pragma unroll
        for (int ntI = 0; ntI < 4; ++ntI)
          acc[ntI] = __builtin_amdgcn_mfma_f32_16x16x32_bf16(asbf(A[i]), breg[ntI][i], acc[ntI], 0, 0, 0);
      CLAIMW4("0", A, 4);
      #pragma unroll
      for (int i = 4; i < 8; ++i)
        #pragma unroll
        for (int ntI = 0; ntI < 4; ++ntI)
          acc[ntI] = __builtin_amdgcn_mfma_f32_16x16x32_bf16(asbf(A[i]), breg[ntI][i], acc[ntI], 0, 0, 0);
    }

    // WAR guard: gate-phase red_lds reads of step t-1 must finish in ALL
    // waves before this step's deposit overwrites them.
    __syncthreads();

    // ---- deposit K-partials (conflict-free banking) ----
    #pragma unroll
    for (int g = 0; g < 4; ++g)
      #pragma unroll
      for (int r = 0; r < 4; ++r)
        red_lds[(((w * 4 + g) * 4 + r) * 4 + qh) * 32 + n16 * 2 + (qh & 1)] = acc[g][r];
    __syncthreads();

    // ---- gate phase: own cell (grow, j0+n16); own partial from register ----
    {
      __bf16* hw = hbuf + (p * 2 + wb) * HBUF_SLAB;
      float gv[4];
      #pragma unroll
      for (int g = 0; g < 4; ++g) {
        float own = (w == 0) ? acc[g][0] : (w == 1) ? acc[g][1]
                  : (w == 2) ? acc[g][2] : acc[g][3];
        float s = own + bias_r[g];
        #pragma unroll
        for (int wo = 0; wo < 4; ++wo)
          if (wo != w)   // w wave-uniform: 3 reads survive per wave
            s += red_lds[(((wo * 4 + g) * 4 + w) * 4 + qh) * 32 + n16 * 2 + (qh & 1)];
        gv[g] = s;
      }
      float i_ = sigmoid_f(gv[0]);
      float f_ = sigmoid_f(gv[1]);
      float g_ = tanh_f(gv[2]);
      float o_ = sigmoid_f(gv[3]);
      float c  = f_ * creg + i_ * g_;
      creg = c;
      float h  = o_ * tanh_f(c);

      // pack 2 adjacent cols via shfl, even lanes store one dword
      union { __bf16 b; unsigned short u; } cv; cv.b = (__bf16)h;
      unsigned int hu = (unsigned int)cv.u;
      unsigned int partner = __shfl_xor(hu, 1);
      if ((n16 & 1) == 0) {
        unsigned int dw = hu | (partner << 16);
        int k = j0 + n16;
        int kk = k >> 5, q2 = (k >> 3) & 3, jj = k & 7;
        sth4<FAST>(hw + kk * 512 + (q2 * 16 + grow) * 8 + jj, dw);
      }
      if (t == SS - 1) hlast[(p * MG + grow) * HH + j0 + n16] = h;
    }

    // ---- per-wave signal: drain own wave's h-stores to the mode's coherence
    // point (L2 in FAST, MALL in SAFE), then lane0 releases the wave-flag ----
    asm volatile("s_waitcnt vmcnt(0)" ::: "memory");
    if (t < SS - 1 && l == 0) {
      sth4<FAST>(gflags + q * 4 + w, (unsigned int)(t + 1));
    }
  }
}

__launch_bounds__(256, 2)
__global__ void lstm_scan(const float* __restrict__ W_hh,
                          const float* __restrict__ b_ih, const float* __restrict__ b_hh,
                          const __bf16* __restrict__ xtp, const __bf16* __restrict__ wihp,
                          __bf16* __restrict__ hbuf, float* __restrict__ hlast,
                          unsigned int* __restrict__ flags, unsigned int* __restrict__ aux) {
  // conflict-free reduce buffer: slot(w,g,r,qh,n16) =
  //   (((w*4+g)*4+r)*4+qh)*32 + n16*2 + (qh&1)   -> bank = 2*n16+(qh&1), 2-way
  __shared__ float red_lds[8192];   // 32 KB

  const int tid = threadIdx.x;
  const int bid = blockIdx.x;
  const int p = bid & 7;                       // batch group == XCD (bid%8)
  const int q = bid >> 3;                      // col slice within group [0,64)
  const int j0 = q * 16;                       // owned h-cols [j0, j0+16)

  const int w = tid >> 6, l = tid & 63;        // wave = K-quarter
  const int n16 = l & 15, qh = l >> 4;
  unsigned int* gflags  = flags + p * 256;     // 64 blocks x 4 wave-flags
  unsigned int* idpub   = aux + p * 64;        // write-once: XCD id + 1
  unsigned int* marker  = aux + 512 + p * 64;  // sc0 rendezvous markers
  unsigned int* outc    = aux + 1024 + p * 64; // write-once: 1=ok 2=timeout

  // ---- publish own XCD id ASAP (sc1, always-correct channel) ----
  unsigned int xcc;
  asm("s_getreg_b32 %0, hwreg(HW_REG_XCC_ID)" : "=s"(xcc));
  const unsigned int idb = (xcc & 0xFu) + 1u;   // nonzero
  if (tid == 0) stg_sc1(idpub + q, idb);

  // ---- W_hh B-fragments persistent in VGPRs (overlaps others' publishes) --
  bf16x8 breg[4][8];
  #pragma unroll
  for (int ntI = 0; ntI < 4; ++ntI) {
    const float* wrow = W_hh + (size_t)(ntI * HH + j0 + n16) * HH;
    #pragma unroll
    for (int i = 0; i < 8; ++i) {
      const float* src = wrow + (w * 8 + i) * 32 + qh * 8;
      bf16x8 bv;
      #pragma unroll
      for (int jj = 0; jj < 8; ++jj) bv[jj] = (__bf16)src[jj];
      breg[ntI][i] = bv;
    }
  }

  const int grow = qh * 4 + w;
  float bias_r[4];
  #pragma unroll
  for (int g = 0; g < 4; ++g)
    bias_r[g] = b_ih[g * HH + j0 + n16] + b_hh[g * HH + j0 + n16];

  // ---- phase 1: gather ids (sc1, unbounded — every block publishes and all
  // 512 are co-resident at 2 blocks/CU). Values are write-once, so every
  // wave of every block sees the identical 64-entry array -> `same` is
  // uniform across the whole group; mixed mode impossible.
  int same;
  {
    const unsigned int* ip = idpub + l;        // lane l <-> block l
    unsigned int f;
    for (;;) {
      f = poll_sc1(ip);
      if (!__ballot(f == 0u)) break;
      __builtin_amdgcn_s_sleep(1);
    }
    unsigned int cm = __builtin_amdgcn_readfirstlane(f);
    same = (__ballot(f != cm) == 0ull) && (cm == idb);
  }

  // ---- phase 2: sc0 rendezvous (bounded spin — PROVES the sc0 channel
  // producer->consumer through the shared L2 before trusting it) ----
  int blockok = 0;
  if (same) {
    if (tid == 0) stg_sc0(marker + q, 0xA5u);
    const unsigned int* mp = marker + l;
    int seen = 0;
    for (int it = 0; it < 4096 && !seen; ++it) {
      unsigned int f = poll_sc0(mp);
      seen = (__ballot(f != 0xA5u) == 0ull);
      if (!seen) __builtin_amdgcn_s_sleep(1);
    }
    blockok = seen;
  }

  // ---- phase 3: referee (sc1; unconditional publish -> deadlock-free) ----
  if (tid == 0) stg_sc1(outc + q, blockok ? 1u : 2u);
  int fastm;
  {
    const unsigned int* op = outc + l;
    unsigned int f;
    for (;;) {
      f = poll_sc1(op);
      if (!__ballot(f == 0u)) break;
      __builtin_amdgcn_s_sleep(1);
    }
    fastm = (__ballot(f != 1u) == 0ull);       // unanimous ok -> FAST
  }

  if (fastm)
    run_scan<true >(p, q, j0, w, l, n16, qh, grow, gflags,
                    breg, bias_r, xtp, wihp, hbuf, hlast, red_lds);
  else
    run_scan<false>(p, q, j0, w, l, n16, qh, grow, gflags,
                    breg, bias_r, xtp, wihp, hbuf, hlast, red_lds);
}

__global__ void fc_kernel(const float* __restrict__ hlast, const float* __restrict__ W_fc,
                          const float* __restrict__ b_fc, float* __restrict__ out) {
  int b = blockIdx.x;            // 128
  int t = threadIdx.x;           // 256
  int o = t >> 2, part = t & 3;
  const float* hr = hlast + b * HH;
  const float* wr = W_fc + o * HH;
  float s = 0.f;
  #pragma unroll 4
  for (int k0 = part * 4; k0 < HH; k0 += 16) {
    float4 hv = *(const float4*)(hr + k0);
    float4 wv = *(const float4*)(wr + k0);
    s += hv.x * wv.x + hv.y * wv.y + hv.z * wv.z + hv.w * wv.w;
  }
  s += __shfl_xor(s, 1);
  s += __shfl_xor(s, 2);
  if (part == 0) out[b * OO + o] = s + b_fc[o];
}

extern "C" void kernel_launch(void* const* d_in, const int* in_sizes, int n_in,
                              void* d_out, int out_size, void* d_ws, size_t ws_size,
                              hipStream_t stream) {
  const float* x    = (const float*)d_in[0];
  const float* mask = (const float*)d_in[1];
  const float* ti   = (const float*)d_in[2];
  const float* W_ih = (const float*)d_in[3];
  const float* W_hh = (const float*)d_in[4];
  const float* b_ih = (const float*)d_in[5];
  const float* b_hh = (const float*)d_in[6];
  const float* W_fc = (const float*)d_in[7];
  const float* b_fc = (const float*)d_in[8];
  float* out = (float*)d_out;

  char* ws = (char*)d_ws;
  unsigned int* flags = (unsigned int*)ws;
  __bf16* hbuf  = (__bf16*)(ws + WS_HBUF);
  float*  hlast = (float*)(ws + WS_HLAST);
  unsigned int* aux = (unsigned int*)(ws + WS_HLAST);  // prologue-only overlap
  __bf16* xtp   = (__bf16*)(ws + WS_XTP);
  __bf16* wihp  = (__bf16*)(ws + WS_WIHP);

  // zero step-flags + aux (sc1, MALL-coherent with all sc1 readers);
  // hbuf needs no init (t=0 skips the h-part).
  flag_init<<<16, 256, 0, stream>>>(flags, aux);

  prepack_kernel<<<(SS * NGROUP * XTP_TP) / 256, 256, 0, stream>>>(x, mask, ti, xtp);
  wih_prepack<<<(GBLK * WIH_BLK) / 256, 256, 0, stream>>>(W_ih, wihp);
  lstm_scan<<<NGROUP * GBLK, 256, 0, stream>>>(W_hh, b_ih, b_hh, xtp, wihp, hbuf, hlast, flags, aux);
  fc_kernel<<<BB, 256, 0, stream>>>(hlast, W_fc, b_fc, out);
}

// Round 6
// 2250.646 us; speedup vs baseline: 1.1523x; 1.1523x over previous
//
#include <hip/hip_runtime.h>
#include <hip/hip_bf16.h>

typedef __bf16 bf16x8 __attribute__((ext_vector_type(8)));
typedef float f32x4 __attribute__((ext_vector_type(4)));
typedef unsigned int u32x4 __attribute__((ext_vector_type(4)));

#define BB   128
#define SS   512
#define DD   128
#define HH   1024
#define OO   64
#define IIN  257

// 8 batch groups (16 rows) x 64 blocks; block owns 16 h-cols (64 gate cols).
// 4 waves = 4 K-quarters, W_hh B-frags persistent in VGPRs.
// Sync-latency ladder so far: sc1/MALL chain ~3.95us/step (r3, 2017us).
// r5: sc0-only FAST channel failed rendezvous (sc0 LOADS may hit stale L1 —
// L1 is never invalidated by remote stores) -> SAFE fallback + timeout cost.
// THIS ROUND: FAST = sc0 stores (write-through, vmcnt-acked at the XCD-shared
// L2) + consumer `buffer_inv sc0` (L1-ONLY invalidate, per-CU, cheap — NOT
// round-1's agent-scope buffer_inv sc1 that nuked L2) before sc0 loads.
// Producer->consumer hops become L2-local (~300cy) instead of MALL (~900cy).
// The rendezvous proves THIS exact channel end-to-end before trusting it;
// any failure -> SAFE = round-3 sc1 protocol bit-exact (G16: placement is a
// performance heuristic, never a correctness dependency).
#define NGROUP 8
#define GBLK   64
#define MG     16
#define KK_H   32     // 1024/32 ksteps
#define KK_X   9      // 288/32

#define XTP_TP    (KK_X*512)      // 4608 bf16 per (t,p)
#define HBUF_SLAB (KK_H*512)      // 16384 bf16 = 32 KB per (p,buf)
#define WIH_BLK   (4*KK_X*512)    // 18432 bf16 per q

// ws layout (bytes): flags 8K | hbuf 512K | hlast 512K | xtp 36M | wihp 2.25M
// The id/marker/outcome aux arrays (8 KB) overlap the FIRST 8 KB of hlast:
// prologue-only use; hlast is written only at t=SS-1, strictly after every
// block's prologue (step-t poll needs all flags >= t).
#define WS_HBUF  8192
#define WS_HLAST 532480
#define WS_XTP   1056768
#define WS_WIHP  38805504

// ---- cache-op helpers.
// sc1 (device scope): bypass L1/L2, coherent at MALL — SAFE mode + referee.
// sc0 (SE scope): store = write-through, vmcnt ack at L2; load = may hit L1
//   (STALE across CUs!) -> always pair with buffer_inv sc0 (L1-only inv).
// NO agent-scope compiler fences anywhere: they emit buffer_inv sc1 /
// buffer_wbl2 which nuke the L2 working set (measured: 10x regression, r1).
__device__ __forceinline__ void stg_sc1(void* p, unsigned int v) {
  asm volatile("global_store_dword %0, %1, off sc1" :: "v"(p), "v"(v));
}
__device__ __forceinline__ void stg_sc0(void* p, unsigned int v) {
  asm volatile("global_store_dword %0, %1, off sc0" :: "v"(p), "v"(v));
}
__device__ __forceinline__ unsigned int poll_sc1(const unsigned int* p) {
  unsigned int f;
  asm volatile("global_load_dword %0, %1, off sc1\n\ts_waitcnt vmcnt(0)" : "=v"(f) : "v"(p));
  return f;
}
// L1-inv + sc0 load: the FAST-mode coherent read (L2-served, same-XCD).
__device__ __forceinline__ unsigned int poll_inv_sc0(const unsigned int* p) {
  unsigned int f;
  asm volatile("buffer_inv sc0\n\t"
               "global_load_dword %0, %1, off sc0\n\t"
               "s_waitcnt vmcnt(0)" : "=v"(f) : "v"(p) : "memory");
  return f;
}
template<bool FAST>
__device__ __forceinline__ u32x4 ldh16(const void* p) {
  u32x4 r;
  if (FAST) asm volatile("global_load_dwordx4 %0, %1, off sc0" : "=v"(r) : "v"(p));
  else      asm volatile("global_load_dwordx4 %0, %1, off sc1" : "=v"(r) : "v"(p));
  return r;
}
template<bool FAST>
__device__ __forceinline__ void sth4(void* p, unsigned int v) {
  if (FAST) stg_sc0(p, v); else stg_sc1(p, v);
}
template<bool FAST>
__device__ __forceinline__ unsigned int pollld(const unsigned int* p) {
  return FAST ? poll_inv_sc0(p) : poll_sc1(p);
}
__device__ __forceinline__ bf16x8 asbf(u32x4 v) {
  union { u32x4 u; bf16x8 h; } c; c.u = v; return c.h;
}

#define CLAIMW4(CNTSTR, A, O)                                        \
  asm volatile("s_waitcnt vmcnt(" CNTSTR ")"                         \
    : "+v"((A)[(O)]), "+v"((A)[(O)+1]), "+v"((A)[(O)+2]), "+v"((A)[(O)+3]))

// Zero step-flags (2048 dwords) + prologue aux arrays (2048 dwords in the
// hlast region) with sc1 stores — MALL-coherent with all sc1 readers.
__global__ void flag_init(unsigned int* __restrict__ flags, unsigned int* __restrict__ aux) {
  int i = blockIdx.x * 256 + threadIdx.x;          // 4096
  if (i < 2048) stg_sc1(flags + i, 0u);
  else          stg_sc1(aux + (i - 2048), 0u);
}

// xtp A-frags (16x16x32 A: m=lane&15, k=kk*32+(lane>>4)*8+j):
// idx = ((t*8+p)*9 + kk)*512 + l*8 + j
__global__ void prepack_kernel(const float* __restrict__ x, const float* __restrict__ mask,
                               const float* __restrict__ ti, __bf16* __restrict__ xtp) {
  int idx = blockIdx.x * 256 + threadIdx.x;        // 18,874,368
  int j = idx & 7, l = (idx >> 3) & 63;
  int rest = idx >> 9;
  int kk = rest % 9;
  int rest2 = rest / 9;
  int p = rest2 & 7;
  int t = rest2 >> 3;
  int b = p * MG + (l & 15);
  int k = kk * 32 + ((l >> 4) << 3) + j;
  float v;
  if (k < 128)       v = x[(b * SS + t) * DD + k];
  else if (k < 256)  v = mask[(b * SS + t) * DD + (k - 128)];
  else if (k == 256) v = ti[b * SS + t];
  else               v = 0.f;
  xtp[idx] = (__bf16)v;
}

// W_ih B-frags per col-slice q: [q][nt][kk][lane][8], nt = gate
__global__ void wih_prepack(const float* __restrict__ W_ih, __bf16* __restrict__ wihp) {
  int idx = blockIdx.x * 256 + threadIdx.x;        // 1,179,648
  int j = idx & 7, l = (idx >> 3) & 63;
  int rest = idx >> 9;
  int kk = rest % 9;
  int rest2 = rest / 9;
  int nt = rest2 & 3, q = rest2 >> 2;
  int col = nt * HH + q * 16 + (l & 15);
  int k = kk * 32 + ((l >> 4) << 3) + j;
  wihp[idx] = (k < IIN) ? (__bf16)W_ih[col * IIN + k] : (__bf16)0.f;
}

__device__ __forceinline__ float sigmoid_f(float v) { return 1.f / (1.f + __expf(-v)); }
__device__ __forceinline__ float tanh_f(float v)    { return 1.f - 2.f / (__expf(2.f * v) + 1.f); }

// Step flags: value = t+1 (1..511). Poll at step t accepts (f - t) <= 1u
// (legit window {t-1,t,t+1}); 0/stale values keep waiting.
template<bool FAST>
__device__ __forceinline__ void run_scan(
    int p, int q, int j0, int w, int l, int n16, int qh, int grow,
    unsigned int* gflags,
    const bf16x8 (&breg)[4][8], const float (&bias_r)[4],
    const __bf16* __restrict__ xtp, const __bf16* __restrict__ wihp,
    __bf16* __restrict__ hbuf, float* __restrict__ hlast, float* red_lds) {
  float creg = 0.f;
  // x-part K split over waves: kk in [xs, xe)
  const int xs = (w == 0) ? 0 : (2 * w + 1);
  const int xe = xs + ((w == 0) ? 3 : 2);

  for (int t = 0; t < SS; ++t) {
    const int rb = t & 1, wb = rb ^ 1;
    f32x4 acc[4];
    #pragma unroll
    for (int ntI = 0; ntI < 4; ++ntI) acc[ntI] = (f32x4){0.f, 0.f, 0.f, 0.f};

    // x-part (this wave's K-slice), pre-poll; A from xtp, B from wihp (cached)
    for (int kk = xs; kk < xe; ++kk) {
      const __bf16* xb = xtp + ((size_t)(t * 8 + p) * KK_X + kk) * 512 + l * 8;
      bf16x8 a = *(const bf16x8*)xb;
      #pragma unroll
      for (int ntI = 0; ntI < 4; ++ntI) {
        bf16x8 b = *(const bf16x8*)(wihp + ((size_t)(q * 4 + ntI) * KK_X + kk) * 512 + l * 8);
        acc[ntI] = __builtin_amdgcn_mfma_f32_16x16x32_bf16(a, b, acc[ntI], 0, 0, 0);
      }
    }

    // per-wave poll: wave w consumes blocks q' in [16w,16w+16) == flags
    // gflags[64w + lane]. Union over the 4 waves covers all 256 flags before
    // the deposit barrier -> slab WAR-safety unchanged. t==0: h0==0 -> skip
    // h-part (hbuf never read before a flag-protected write; no hbuf init).
    if (t > 0) {
      {
        const unsigned int tgt = (unsigned int)t;
        const unsigned int* fp = gflags + (w << 6) + l;
        for (;;) {
          unsigned int f = pollld<FAST>(fp);
          if (!__ballot((f - tgt) > 1u)) break;
          __builtin_amdgcn_s_sleep(1);
        }
        __builtin_amdgcn_sched_barrier(0);
      }
      // FAST: one more L1-inv so the h-lines (last touched at t-2, possibly
      // still in this CU's L1) are re-read from the XCD-shared L2.
      if (FAST) asm volatile("buffer_inv sc0" ::: "memory");

      // h-part: this wave's K-quarter (8 ksteps). A via mode path, B VGPRs.
      const __bf16* hbL = hbuf + (p * 2 + rb) * HBUF_SLAB + (w * 8) * 512 + l * 8;
      u32x4 A[8];
      #pragma unroll
      for (int i = 0; i < 8; ++i) A[i] = ldh16<FAST>(hbL + i * 512);

      CLAIMW4("4", A, 0);
      #pragma unroll
      for (int i = 0; i < 4; ++i)
        #pragma unroll
        for (int ntI = 0; ntI < 4; ++ntI)
          acc[ntI] = __builtin_amdgcn_mfma_f32_16x16x32_bf16(asbf(A[i]), breg[ntI][i], acc[ntI], 0, 0, 0);
      CLAIMW4("0", A, 4);
      #pragma unroll
      for (int i = 4; i < 8; ++i)
        #pragma unroll
        for (int ntI = 0; ntI < 4; ++ntI)
          acc[ntI] = __builtin_amdgcn_mfma_f32_16x16x32_bf16(asbf(A[i]), breg[ntI][i], acc[ntI], 0, 0, 0);
    }

    // WAR guard: gate-phase red_lds reads of step t-1 must finish in ALL
    // waves before this step's deposit overwrites them.
    __syncthreads();

    // ---- deposit K-partials (conflict-free banking) ----
    #pragma unroll
    for (int g = 0; g < 4; ++g)
      #pragma unroll
      for (int r = 0; r < 4; ++r)
        red_lds[(((w * 4 + g) * 4 + r) * 4 + qh) * 32 + n16 * 2 + (qh & 1)] = acc[g][r];
    __syncthreads();

    // ---- gate phase: own cell (grow, j0+n16); own partial from register ----
    {
      __bf16* hw = hbuf + (p * 2 + wb) * HBUF_SLAB;
      float gv[4];
      #pragma unroll
      for (int g = 0; g < 4; ++g) {
        float own = (w == 0) ? acc[g][0] : (w == 1) ? acc[g][1]
                  : (w == 2) ? acc[g][2] : acc[g][3];
        float s = own + bias_r[g];
        #pragma unroll
        for (int wo = 0; wo < 4; ++wo)
          if (wo != w)   // w wave-uniform: 3 reads survive per wave
            s += red_lds[(((wo * 4 + g) * 4 + w) * 4 + qh) * 32 + n16 * 2 + (qh & 1)];
        gv[g] = s;
      }
      float i_ = sigmoid_f(gv[0]);
      float f_ = sigmoid_f(gv[1]);
      float g_ = tanh_f(gv[2]);
      float o_ = sigmoid_f(gv[3]);
      float c  = f_ * creg + i_ * g_;
      creg = c;
      float h  = o_ * tanh_f(c);

      // pack 2 adjacent cols via shfl, even lanes store one dword
      union { __bf16 b; unsigned short u; } cv; cv.b = (__bf16)h;
      unsigned int hu = (unsigned int)cv.u;
      unsigned int partner = __shfl_xor(hu, 1);
      if ((n16 & 1) == 0) {
        unsigned int dw = hu | (partner << 16);
        int k = j0 + n16;
        int kk = k >> 5, q2 = (k >> 3) & 3, jj = k & 7;
        sth4<FAST>(hw + kk * 512 + (q2 * 16 + grow) * 8 + jj, dw);
      }
      if (t == SS - 1) hlast[(p * MG + grow) * HH + j0 + n16] = h;
    }

    // ---- per-wave signal: drain own wave's h-stores to the mode's coherence
    // point (sc0 -> L2 ack in FAST; sc1 -> MALL ack in SAFE), then lane0
    // releases the wave-flag via the same path ----
    asm volatile("s_waitcnt vmcnt(0)" ::: "memory");
    if (t < SS - 1 && l == 0) {
      sth4<FAST>(gflags + q * 4 + w, (unsigned int)(t + 1));
    }
  }
}

__launch_bounds__(256, 2)
__global__ void lstm_scan(const float* __restrict__ W_hh,
                          const float* __restrict__ b_ih, const float* __restrict__ b_hh,
                          const __bf16* __restrict__ xtp, const __bf16* __restrict__ wihp,
                          __bf16* __restrict__ hbuf, float* __restrict__ hlast,
                          unsigned int* __restrict__ flags, unsigned int* __restrict__ aux) {
  // conflict-free reduce buffer: slot(w,g,r,qh,n16) =
  //   (((w*4+g)*4+r)*4+qh)*32 + n16*2 + (qh&1)   -> bank = 2*n16+(qh&1), 2-way
  __shared__ float red_lds[8192];   // 32 KB

  const int tid = threadIdx.x;
  const int bid = blockIdx.x;
  const int p = bid & 7;                       // batch group == XCD (bid%8)
  const int q = bid >> 3;                      // col slice within group [0,64)
  const int j0 = q * 16;                       // owned h-cols [j0, j0+16)

  const int w = tid >> 6, l = tid & 63;        // wave = K-quarter
  const int n16 = l & 15, qh = l >> 4;
  unsigned int* gflags  = flags + p * 256;     // 64 blocks x 4 wave-flags
  unsigned int* idpub   = aux + p * 64;        // write-once: XCD id + 1
  unsigned int* marker  = aux + 512 + p * 64;  // rendezvous markers
  unsigned int* outc    = aux + 1024 + p * 64; // write-once: 1=ok 2=timeout

  // ---- publish own XCD id ASAP (sc1, always-correct channel) ----
  unsigned int xcc;
  asm("s_getreg_b32 %0, hwreg(HW_REG_XCC_ID)" : "=s"(xcc));
  const unsigned int idb = (xcc & 0xFu) + 1u;   // nonzero
  if (tid == 0) stg_sc1(idpub + q, idb);

  // ---- W_hh B-fragments persistent in VGPRs (overlaps others' publishes) --
  bf16x8 breg[4][8];
  #pragma unroll
  for (int ntI = 0; ntI < 4; ++ntI) {
    const float* wrow = W_hh + (size_t)(ntI * HH + j0 + n16) * HH;
    #pragma unroll
    for (int i = 0; i < 8; ++i) {
      const float* src = wrow + (w * 8 + i) * 32 + qh * 8;
      bf16x8 bv;
      #pragma unroll
      for (int jj = 0; jj < 8; ++jj) bv[jj] = (__bf16)src[jj];
      breg[ntI][i] = bv;
    }
  }

  const int grow = qh * 4 + w;
  float bias_r[4];
  #pragma unroll
  for (int g = 0; g < 4; ++g)
    bias_r[g] = b_ih[g * HH + j0 + n16] + b_hh[g * HH + j0 + n16];

  // ---- phase 1: gather ids (sc1, unbounded — every block publishes and all
  // 512 are co-resident at 2 blocks/CU). Write-once values -> every wave of
  // every block computes the identical `same` -> uniform across the group.
  int same;
  {
    const unsigned int* ip = idpub + l;        // lane l <-> block l
    unsigned int f;
    for (;;) {
      f = poll_sc1(ip);
      if (!__ballot(f == 0u)) break;
      __builtin_amdgcn_s_sleep(1);
    }
    unsigned int cm = __builtin_amdgcn_readfirstlane(f);
    same = (__ballot(f != cm) == 0ull) && (cm == idb);
  }

  // ---- phase 2: rendezvous over the EXACT FAST channel (sc0 store ->
  // inv-L1 + sc0 load). Bounded spin; proves cross-CU visibility through the
  // XCD-shared L2 before trusting it for the scan.
  int blockok = 0;
  if (same) {
    if (tid == 0) stg_sc0(marker + q, 0xA5u);
    const unsigned int* mp = marker + l;
    int seen = 0;
    for (int it = 0; it < 1024 && !seen; ++it) {
      unsigned int f = poll_inv_sc0(mp);
      seen = (__ballot(f != 0xA5u) == 0ull);
      if (!seen) __builtin_amdgcn_s_sleep(1);
    }
    blockok = seen;
  }

  // ---- phase 3: referee (sc1; unconditional publish -> deadlock-free) ----
  if (tid == 0) stg_sc1(outc + q, blockok ? 1u : 2u);
  int fastm;
  {
    const unsigned int* op = outc + l;
    unsigned int f;
    for (;;) {
      f = poll_sc1(op);
      if (!__ballot(f == 0u)) break;
      __builtin_amdgcn_s_sleep(1);
    }
    fastm = (__ballot(f != 1u) == 0ull);       // unanimous ok -> FAST
  }

  if (fastm)
    run_scan<true >(p, q, j0, w, l, n16, qh, grow, gflags,
                    breg, bias_r, xtp, wihp, hbuf, hlast, red_lds);
  else
    run_scan<false>(p, q, j0, w, l, n16, qh, grow, gflags,
                    breg, bias_r, xtp, wihp, hbuf, hlast, red_lds);
}

__global__ void fc_kernel(const float* __restrict__ hlast, const float* __restrict__ W_fc,
                          const float* __restrict__ b_fc, float* __restrict__ out) {
  int b = blockIdx.x;            // 128
  int t = threadIdx.x;           // 256
  int o = t >> 2, part = t & 3;
  const float* hr = hlast + b * HH;
  const float* wr = W_fc + o * HH;
  float s = 0.f;
  #pragma unroll 4
  for (int k0 = part * 4; k0 < HH; k0 += 16) {
    float4 hv = *(const float4*)(hr + k0);
    float4 wv = *(const float4*)(wr + k0);
    s += hv.x * wv.x + hv.y * wv.y + hv.z * wv.z + hv.w * wv.w;
  }
  s += __shfl_xor(s, 1);
  s += __shfl_xor(s, 2);
  if (part == 0) out[b * OO + o] = s + b_fc[o];
}

extern "C" void kernel_launch(void* const* d_in, const int* in_sizes, int n_in,
                              void* d_out, int out_size, void* d_ws, size_t ws_size,
                              hipStream_t stream) {
  const float* x    = (const float*)d_in[0];
  const float* mask = (const float*)d_in[1];
  const float* ti   = (const float*)d_in[2];
  const float* W_ih = (const float*)d_in[3];
  const float* W_hh = (const float*)d_in[4];
  const float* b_ih = (const float*)d_in[5];
  const float* b_hh = (const float*)d_in[6];
  const float* W_fc = (const float*)d_in[7];
  const float* b_fc = (const float*)d_in[8];
  float* out = (float*)d_out;

  char* ws = (char*)d_ws;
  unsigned int* flags = (unsigned int*)ws;
  __bf16* hbuf  = (__bf16*)(ws + WS_HBUF);
  float*  hlast = (float*)(ws + WS_HLAST);
  unsigned int* aux = (unsigned int*)(ws + WS_HLAST);  // prologue-only overlap
  __bf16* xtp   = (__bf16*)(ws + WS_XTP);
  __bf16* wihp  = (__bf16*)(ws + WS_WIHP);

  // zero step-flags + aux (sc1, MALL-coherent with all sc1 readers);
  // hbuf needs no init (t=0 skips the h-part).
  flag_init<<<16, 256, 0, stream>>>(flags, aux);

  prepack_kernel<<<(SS * NGROUP * XTP_TP) / 256, 256, 0, stream>>>(x, mask, ti, xtp);
  wih_prepack<<<(GBLK * WIH_BLK) / 256, 256, 0, stream>>>(W_ih, wihp);
  lstm_scan<<<NGROUP * GBLK, 256, 0, stream>>>(W_hh, b_ih, b_hh, xtp, wihp, hbuf, hlast, flags, aux);
  fc_kernel<<<BB, 256, 0, stream>>>(hlast, W_fc, b_fc, out);
}

// Round 7
// 2244.259 us; speedup vs baseline: 1.1555x; 1.0028x over previous
//
#include <hip/hip_runtime.h>
#include <hip/hip_bf16.h>

typedef __bf16 bf16x8 __attribute__((ext_vector_type(8)));
typedef float f32x4 __attribute__((ext_vector_type(4)));
typedef unsigned int u32x4 __attribute__((ext_vector_type(4)));

#define BB   128
#define SS   512
#define DD   128
#define HH   1024
#define OO   64
#define IIN  257

// 8 batch groups (16 rows) x 64 blocks; block owns 16 h-cols (64 gate cols).
// 4 waves = 4 K-quarters, W_hh B-frags persistent in VGPRs.
// Cache-scope model (fits r4 hang, r5 timeout, r6 FAST-at-SAFE-speed):
//   plain store (sc=00): write-through L1, terminates DIRTY IN L2 (L2 is WB).
//   sc0 store: writes through PAST L2 (toward MALL).
//   plain load: may hit stale L1; after `buffer_inv sc0` (L1-ONLY inv, the
//     LLVM workgroup-acquire op — NOT r1's agent-scope L2-nuke) it is served
//     by the XCD-shared L2.
//   sc0 load: bypasses L2 to MALL (why r6 ran FAST at MALL speed).
//   sc1 ops: MALL-coherent, any placement (SAFE mode + referee).
// FAST channel (same-XCD only, runtime-proven): plain stores -> vmcnt(0)
// (ack at L2) -> plain flag store; consumer: buffer_inv sc0 + plain load.
// Phase-1 placement check (s_getreg XCC_ID) + phase-2 rendezvous over THIS
// exact channel + sc1 referee -> unanimous FAST or bit-exact round-3 SAFE.
// Placement stays a performance heuristic, never a correctness dependency.
#define NGROUP 8
#define GBLK   64
#define MG     16
#define KK_H   32     // 1024/32 ksteps
#define KK_X   9      // 288/32

#define XTP_TP    (KK_X*512)      // 4608 bf16 per (t,p)
#define HBUF_SLAB (KK_H*512)      // 16384 bf16 = 32 KB per (p,buf)
#define WIH_BLK   (4*KK_X*512)    // 18432 bf16 per q

// ws layout (bytes): flags 8K | hbuf 512K | hlast 512K | xtp 36M | wihp 2.25M
// aux arrays (8 KB) overlap the FIRST 8 KB of hlast: prologue-only use;
// hlast is written only at t=SS-1, strictly after every block's prologue.
#define WS_HBUF  8192
#define WS_HLAST 532480
#define WS_XTP   1056768
#define WS_WIHP  38805504

__device__ __forceinline__ void stg_sc1(void* p, unsigned int v) {
  asm volatile("global_store_dword %0, %1, off sc1" :: "v"(p), "v"(v));
}
__device__ __forceinline__ void stg_plain(void* p, unsigned int v) {
  asm volatile("global_store_dword %0, %1, off" :: "v"(p), "v"(v));
}
__device__ __forceinline__ unsigned int poll_sc1(const unsigned int* p) {
  unsigned int f;
  asm volatile("global_load_dword %0, %1, off sc1\n\ts_waitcnt vmcnt(0)" : "=v"(f) : "v"(p));
  return f;
}
// FAST coherent read: L1-only invalidate, then plain load served by the
// XCD-shared L2 (where producers' plain stores terminate dirty).
__device__ __forceinline__ unsigned int poll_inv_plain(const unsigned int* p) {
  unsigned int f;
  asm volatile("buffer_inv sc0\n\t"
               "global_load_dword %0, %1, off\n\t"
               "s_waitcnt vmcnt(0)" : "=v"(f) : "v"(p) : "memory");
  return f;
}
template<bool FAST>
__device__ __forceinline__ u32x4 ldh16(const void* p) {
  u32x4 r;
  if (FAST) asm volatile("global_load_dwordx4 %0, %1, off"     : "=v"(r) : "v"(p));
  else      asm volatile("global_load_dwordx4 %0, %1, off sc1" : "=v"(r) : "v"(p));
  return r;
}
template<bool FAST>
__device__ __forceinline__ void sth4(void* p, unsigned int v) {
  if (FAST) stg_plain(p, v); else stg_sc1(p, v);
}
template<bool FAST>
__device__ __forceinline__ unsigned int pollld(const unsigned int* p) {
  return FAST ? poll_inv_plain(p) : poll_sc1(p);
}
__device__ __forceinline__ bf16x8 asbf(u32x4 v) {
  union { u32x4 u; bf16x8 h; } c; c.u = v; return c.h;
}

#define CLAIMW4(CNTSTR, A, O)                                        \
  asm volatile("s_waitcnt vmcnt(" CNTSTR ")"                         \
    : "+v"((A)[(O)]), "+v"((A)[(O)+1]), "+v"((A)[(O)+2]), "+v"((A)[(O)+3]))

// Zero step-flags (2048 dwords) + prologue aux arrays (2048 dwords in the
// hlast region) with sc1 stores — MALL-coherent with all sc1 readers. L2
// copies of prior-launch plain-stored flags are handled by the runtime's
// end-of-dispatch L2 writeback/invalidate (evidenced by hlast's plain-store
// -> cross-XCD fc_kernel read working for 6 rounds).
__global__ void flag_init(unsigned int* __restrict__ flags, unsigned int* __restrict__ aux) {
  int i = blockIdx.x * 256 + threadIdx.x;          // 4096
  if (i < 2048) stg_sc1(flags + i, 0u);
  else          stg_sc1(aux + (i - 2048), 0u);
}

// xtp A-frags (16x16x32 A: m=lane&15, k=kk*32+(lane>>4)*8+j):
// idx = ((t*8+p)*9 + kk)*512 + l*8 + j
__global__ void prepack_kernel(const float* __restrict__ x, const float* __restrict__ mask,
                               const float* __restrict__ ti, __bf16* __restrict__ xtp) {
  int idx = blockIdx.x * 256 + threadIdx.x;        // 18,874,368
  int j = idx & 7, l = (idx >> 3) & 63;
  int rest = idx >> 9;
  int kk = rest % 9;
  int rest2 = rest / 9;
  int p = rest2 & 7;
  int t = rest2 >> 3;
  int b = p * MG + (l & 15);
  int k = kk * 32 + ((l >> 4) << 3) + j;
  float v;
  if (k < 128)       v = x[(b * SS + t) * DD + k];
  else if (k < 256)  v = mask[(b * SS + t) * DD + (k - 128)];
  else if (k == 256) v = ti[b * SS + t];
  else               v = 0.f;
  xtp[idx] = (__bf16)v;
}

// W_ih B-frags per col-slice q: [q][nt][kk][lane][8], nt = gate
__global__ void wih_prepack(const float* __restrict__ W_ih, __bf16* __restrict__ wihp) {
  int idx = blockIdx.x * 256 + threadIdx.x;        // 1,179,648
  int j = idx & 7, l = (idx >> 3) & 63;
  int rest = idx >> 9;
  int kk = rest % 9;
  int rest2 = rest / 9;
  int nt = rest2 & 3, q = rest2 >> 2;
  int col = nt * HH + q * 16 + (l & 15);
  int k = kk * 32 + ((l >> 4) << 3) + j;
  wihp[idx] = (k < IIN) ? (__bf16)W_ih[col * IIN + k] : (__bf16)0.f;
}

__device__ __forceinline__ float sigmoid_f(float v) { return 1.f / (1.f + __expf(-v)); }
__device__ __forceinline__ float tanh_f(float v)    { return 1.f - 2.f / (__expf(2.f * v) + 1.f); }

// Step flags: value = t+1 (1..511). Poll at step t accepts (f - t) <= 1u
// (legit window {t-1,t,t+1}); 0/stale values keep waiting.
template<bool FAST>
__device__ __forceinline__ void run_scan(
    int p, int q, int j0, int w, int l, int n16, int qh, int grow,
    unsigned int* gflags,
    const bf16x8 (&breg)[4][8], const float (&bias_r)[4],
    const __bf16* __restrict__ xtp, const __bf16* __restrict__ wihp,
    __bf16* __restrict__ hbuf, float* __restrict__ hlast, float* red_lds) {
  float creg = 0.f;
  // x-part K split over waves: kk in [xs, xe)
  const int xs = (w == 0) ? 0 : (2 * w + 1);
  const int xe = xs + ((w == 0) ? 3 : 2);

  for (int t = 0; t < SS; ++t) {
    const int rb = t & 1, wb = rb ^ 1;
    f32x4 acc[4];
    #pragma unroll
    for (int ntI = 0; ntI < 4; ++ntI) acc[ntI] = (f32x4){0.f, 0.f, 0.f, 0.f};

    // x-part (this wave's K-slice), pre-poll; A from xtp, B from wihp (cached)
    for (int kk = xs; kk < xe; ++kk) {
      const __bf16* xb = xtp + ((size_t)(t * 8 + p) * KK_X + kk) * 512 + l * 8;
      bf16x8 a = *(const bf16x8*)xb;
      #pragma unroll
      for (int ntI = 0; ntI < 4; ++ntI) {
        bf16x8 b = *(const bf16x8*)(wihp + ((size_t)(q * 4 + ntI) * KK_X + kk) * 512 + l * 8);
        acc[ntI] = __builtin_amdgcn_mfma_f32_16x16x32_bf16(a, b, acc[ntI], 0, 0, 0);
      }
    }

    // per-wave poll: wave w consumes blocks q' in [16w,16w+16) == flags
    // gflags[64w + lane]. Union over the 4 waves covers all 256 flags before
    // the deposit barrier -> slab WAR-safety unchanged. t==0: h0==0 -> skip
    // h-part (hbuf never read before a flag-protected write; no hbuf init).
    // FAST: each poll iteration invs L1 then reads from L2; the final
    // iteration's inv also covers the h-lines (touched last at t-2, not
    // re-touched between that inv and the h-loads below).
    if (t > 0) {
      {
        const unsigned int tgt = (unsigned int)t;
        const unsigned int* fp = gflags + (w << 6) + l;
        for (;;) {
          unsigned int f = pollld<FAST>(fp);
          if (!__ballot((f - tgt) > 1u)) break;
          __builtin_amdgcn_s_sleep(1);
        }
        __builtin_amdgcn_sched_barrier(0);
      }

      // h-part: this wave's K-quarter (8 ksteps). A via mode path, B VGPRs.
      const __bf16* hbL = hbuf + (p * 2 + rb) * HBUF_SLAB + (w * 8) * 512 + l * 8;
      u32x4 A[8];
      #pragma unroll
      for (int i = 0; i < 8; ++i) A[i] = ldh16<FAST>(hbL + i * 512);

      CLAIMW4("4", A, 0);
      #pragma unroll
      for (int i = 0; i < 4; ++i)
        #pragma unroll
        for (int ntI = 0; ntI < 4; ++ntI)
          acc[ntI] = __builtin_amdgcn_mfma_f32_16x16x32_bf16(asbf(A[i]), breg[ntI][i], acc[ntI], 0, 0, 0);
      CLAIMW4("0", A, 4);
      #pragma unroll
      for (int i = 4; i < 8; ++i)
        #pragma unroll
        for (int ntI = 0; ntI < 4; ++ntI)
          acc[ntI] = __builtin_amdgcn_mfma_f32_16x16x32_bf16(asbf(A[i]), breg[ntI][i], acc[ntI], 0, 0, 0);
    }

    // WAR guard: gate-phase red_lds reads of step t-1 must finish in ALL
    // waves before this step's deposit overwrites them.
    __syncthreads();

    // ---- deposit K-partials (conflict-free banking) ----
    #pragma unroll
    for (int g = 0; g < 4; ++g)
      #pragma unroll
      for (int r = 0; r < 4; ++r)
        red_lds[(((w * 4 + g) * 4 + r) * 4 + qh) * 32 + n16 * 2 + (qh & 1)] = acc[g][r];
    __syncthreads();

    // ---- gate phase: own cell (grow, j0+n16); own partial from register ----
    {
      __bf16* hw = hbuf + (p * 2 + wb) * HBUF_SLAB;
      float gv[4];
      #pragma unroll
      for (int g = 0; g < 4; ++g) {
        float own = (w == 0) ? acc[g][0] : (w == 1) ? acc[g][1]
                  : (w == 2) ? acc[g][2] : acc[g][3];
        float s = own + bias_r[g];
        #pragma unroll
        for (int wo = 0; wo < 4; ++wo)
          if (wo != w)   // w wave-uniform: 3 reads survive per wave
            s += red_lds[(((wo * 4 + g) * 4 + w) * 4 + qh) * 32 + n16 * 2 + (qh & 1)];
        gv[g] = s;
      }
      float i_ = sigmoid_f(gv[0]);
      float f_ = sigmoid_f(gv[1]);
      float g_ = tanh_f(gv[2]);
      float o_ = sigmoid_f(gv[3]);
      float c  = f_ * creg + i_ * g_;
      creg = c;
      float h  = o_ * tanh_f(c);

      // pack 2 adjacent cols via shfl, even lanes store one dword
      union { __bf16 b; unsigned short u; } cv; cv.b = (__bf16)h;
      unsigned int hu = (unsigned int)cv.u;
      unsigned int partner = __shfl_xor(hu, 1);
      if ((n16 & 1) == 0) {
        unsigned int dw = hu | (partner << 16);
        int k = j0 + n16;
        int kk = k >> 5, q2 = (k >> 3) & 3, jj = k & 7;
        sth4<FAST>(hw + kk * 512 + (q2 * 16 + grow) * 8 + jj, dw);
      }
      if (t == SS - 1) hlast[(p * MG + grow) * HH + j0 + n16] = h;
    }

    // ---- per-wave signal: drain own wave's h-stores to the mode's
    // coherence point (L2 in FAST — plain stores terminate there; MALL in
    // SAFE), then lane0 releases the wave-flag via the same path ----
    asm volatile("s_waitcnt vmcnt(0)" ::: "memory");
    if (t < SS - 1 && l == 0) {
      sth4<FAST>(gflags + q * 4 + w, (unsigned int)(t + 1));
    }
  }
}

__launch_bounds__(256, 2)
__global__ void lstm_scan(const float* __restrict__ W_hh,
                          const float* __restrict__ b_ih, const float* __restrict__ b_hh,
                          const __bf16* __restrict__ xtp, const __bf16* __restrict__ wihp,
                          __bf16* __restrict__ hbuf, float* __restrict__ hlast,
                          unsigned int* __restrict__ flags, unsigned int* __restrict__ aux) {
  // conflict-free reduce buffer: slot(w,g,r,qh,n16) =
  //   (((w*4+g)*4+r)*4+qh)*32 + n16*2 + (qh&1)   -> bank = 2*n16+(qh&1), 2-way
  __shared__ float red_lds[8192];   // 32 KB

  const int tid = threadIdx.x;
  const int bid = blockIdx.x;
  const int p = bid & 7;                       // batch group == XCD (bid%8)
  const int q = bid >> 3;                      // col slice within group [0,64)
  const int j0 = q * 16;                       // owned h-cols [j0, j0+16)

  const int w = tid >> 6, l = tid & 63;        // wave = K-quarter
  const int n16 = l & 15, qh = l >> 4;
  unsigned int* gflags  = flags + p * 256;     // 64 blocks x 4 wave-flags
  unsigned int* idpub   = aux + p * 64;        // write-once: XCD id + 1
  unsigned int* marker  = aux + 512 + p * 64;  // rendezvous markers
  unsigned int* outc    = aux + 1024 + p * 64; // write-once: 1=ok 2=timeout

  // ---- publish own XCD id ASAP (sc1, always-correct channel) ----
  unsigned int xcc;
  asm("s_getreg_b32 %0, hwreg(HW_REG_XCC_ID)" : "=s"(xcc));
  const unsigned int idb = (xcc & 0xFu) + 1u;   // nonzero
  if (tid == 0) stg_sc1(idpub + q, idb);

  // ---- W_hh B-fragments persistent in VGPRs (overlaps others' publishes) --
  bf16x8 breg[4][8];
  #pragma unroll
  for (int ntI = 0; ntI < 4; ++ntI) {
    const float* wrow = W_hh + (size_t)(ntI * HH + j0 + n16) * HH;
    #pragma unroll
    for (int i = 0; i < 8; ++i) {
      const float* src = wrow + (w * 8 + i) * 32 + qh * 8;
      bf16x8 bv;
      #pragma unroll
      for (int jj = 0; jj < 8; ++jj) bv[jj] = (__bf16)src[jj];
      breg[ntI][i] = bv;
    }
  }

  const int grow = qh * 4 + w;
  float bias_r[4];
  #pragma unroll
  for (int g = 0; g < 4; ++g)
    bias_r[g] = b_ih[g * HH + j0 + n16] + b_hh[g * HH + j0 + n16];

  // ---- phase 1: gather ids (sc1, unbounded — every block publishes and all
  // 512 are co-resident at 2 blocks/CU). Write-once values -> every wave of
  // every block computes the identical `same` -> uniform across the group.
  int same;
  {
    const unsigned int* ip = idpub + l;        // lane l <-> block l
    unsigned int f;
    for (;;) {
      f = poll_sc1(ip);
      if (!__ballot(f == 0u)) break;
      __builtin_amdgcn_s_sleep(1);
    }
    unsigned int cm = __builtin_amdgcn_readfirstlane(f);
    same = (__ballot(f != cm) == 0ull) && (cm == idb);
  }

  // ---- phase 2: rendezvous over the EXACT FAST channel (plain store ->
  // buffer_inv sc0 + plain load). Bounded spin; proves cross-CU visibility
  // through the XCD-shared L2 before trusting it for the scan.
  int blockok = 0;
  if (same) {
    if (tid == 0) stg_plain(marker + q, 0xA5u);
    const unsigned int* mp = marker + l;
    int seen = 0;
    for (int it = 0; it < 1024 && !seen; ++it) {
      unsigned int f = poll_inv_plain(mp);
      seen = (__ballot(f != 0xA5u) == 0ull);
      if (!seen) __builtin_amdgcn_s_sleep(1);
    }
    blockok = seen;
  }

  // ---- phase 3: referee (sc1; unconditional publish -> deadlock-free) ----
  if (tid == 0) stg_sc1(outc + q, blockok ? 1u : 2u);
  int fastm;
  {
    const unsigned int* op = outc + l;
    unsigned int f;
    for (;;) {
      f = poll_sc1(op);
      if (!__ballot(f == 0u)) break;
      __builtin_amdgcn_s_sleep(1);
    }
    fastm = (__ballot(f != 1u) == 0ull);       // unanimous ok -> FAST
  }

  if (fastm)
    run_scan<true >(p, q, j0, w, l, n16, qh, grow, gflags,
                    breg, bias_r, xtp, wihp, hbuf, hlast, red_lds);
  else
    run_scan<false>(p, q, j0, w, l, n16, qh, grow, gflags,
                    breg, bias_r, xtp, wihp, hbuf, hlast, red_lds);
}

__global__ void fc_kernel(const float* __restrict__ hlast, const float* __restrict__ W_fc,
                          const float* __restrict__ b_fc, float* __restrict__ out) {
  int b = blockIdx.x;            // 128
  int t = threadIdx.x;           // 256
  int o = t >> 2, part = t & 3;
  const float* hr = hlast + b * HH;
  const float* wr = W_fc + o * HH;
  float s = 0.f;
  #pragma unroll 4
  for (int k0 = part * 4; k0 < HH; k0 += 16) {
    float4 hv = *(const float4*)(hr + k0);
    float4 wv = *(const float4*)(wr + k0);
    s += hv.x * wv.x + hv.y * wv.y + hv.z * wv.z + hv.w * wv.w;
  }
  s += __shfl_xor(s, 1);
  s += __shfl_xor(s, 2);
  if (part == 0) out[b * OO + o] = s + b_fc[o];
}

extern "C" void kernel_launch(void* const* d_in, const int* in_sizes, int n_in,
                              void* d_out, int out_size, void* d_ws, size_t ws_size,
                              hipStream_t stream) {
  const float* x    = (const float*)d_in[0];
  const float* mask = (const float*)d_in[1];
  const float* ti   = (const float*)d_in[2];
  const float* W_ih = (const float*)d_in[3];
  const float* W_hh = (const float*)d_in[4];
  const float* b_ih = (const float*)d_in[5];
  const float* b_hh = (const float*)d_in[6];
  const float* W_fc = (const float*)d_in[7];
  const float* b_fc = (const float*)d_in[8];
  float* out = (float*)d_out;

  char* ws = (char*)d_ws;
  unsigned int* flags = (unsigned int*)ws;
  __bf16* hbuf  = (__bf16*)(ws + WS_HBUF);
  float*  hlast = (float*)(ws + WS_HLAST);
  unsigned int* aux = (unsigned int*)(ws + WS_HLAST);  // prologue-only overlap
  __bf16* xtp   = (__bf16*)(ws + WS_XTP);
  __bf16* wihp  = (__bf16*)(ws + WS_WIHP);

  // zero step-flags + aux (sc1, MALL-coherent with all sc1 readers);
  // hbuf needs no init (t=0 skips the h-part).
  flag_init<<<16, 256, 0, stream>>>(flags, aux);

  prepack_kernel<<<(SS * NGROUP * XTP_TP) / 256, 256, 0, stream>>>(x, mask, ti, xtp);
  wih_prepack<<<(GBLK * WIH_BLK) / 256, 256, 0, stream>>>(W_ih, wihp);
  lstm_scan<<<NGROUP * GBLK, 256, 0, stream>>>(W_hh, b_ih, b_hh, xtp, wihp, hbuf, hlast, flags, aux);
  fc_kernel<<<BB, 256, 0, stream>>>(hlast, W_fc, b_fc, out);
}

// Round 8
// 2064.354 us; speedup vs baseline: 1.2562x; 1.0871x over previous
//
#include <hip/hip_runtime.h>
#include <hip/hip_bf16.h>

typedef __bf16 bf16x8 __attribute__((ext_vector_type(8)));
typedef float f32x4 __attribute__((ext_vector_type(4)));
typedef unsigned int u32x4 __attribute__((ext_vector_type(4)));

#define BB   128
#define SS   512
#define DD   128
#define HH   1024
#define OO   64
#define IIN  257

// 8 batch groups (16 rows) x 64 blocks; block owns 16 h-cols (64 gate cols).
// 4 waves = 4 K-quarters, W_hh B-frags persistent in VGPRs.
// Protocol: sc1 (MALL-coherent) handshake — the ONLY channel that works.
// Closed lines of attack (measured):
//   r1: agent fences (buffer_inv sc1/wbl2) -> 10x regression (L2 nuked).
//   r3: XCD co-location (p=bid&7): FETCH 702->164 MB, time unchanged (sc1
//       always pays MALL RTT; placement verified correct in r7 phase-1).
//   r5/r6/r7: every same-XCD L2 fast-channel variant (sc0/sc0, sc0-st/inv+
//       sc0-ld, plain-st/inv+plain-ld) failed a runtime rendezvous probe ->
//       no HIP-reachable L2-coherent cross-CU path on gfx950.
// This version: r3 core, minus verification overhead, minus one barrier/step
// (red_lds double-buffered: deposit(t)->buf[t&1], reuse at t+2 is fenced by
// the surviving deposit->gate barrier + flag-window skew bound <= 1 step).
#define NGROUP 8
#define GBLK   64
#define MG     16
#define KK_H   32     // 1024/32 ksteps
#define KK_X   9      // 288/32

#define XTP_TP    (KK_X*512)      // 4608 bf16 per (t,p)
#define HBUF_SLAB (KK_H*512)      // 16384 bf16 = 32 KB per (p,buf)
#define WIH_BLK   (4*KK_X*512)    // 18432 bf16 per q

// ws layout (bytes): flags 8K | hbuf 512K | hlast 512K | xtp 36M | wihp 2.25M
#define WS_HBUF  8192
#define WS_HLAST 532480
#define WS_XTP   1056768
#define WS_WIHP  38805504

// ---- device-scope (sc1) ops: bypass L1/L2, coherent at MALL. NO agent-scope
// compiler fences anywhere (r1: 10x regression).
__device__ __forceinline__ u32x4 ldg_dev16(const void* p) {
  u32x4 r;
  asm volatile("global_load_dwordx4 %0, %1, off sc1" : "=v"(r) : "v"(p));
  return r;
}
__device__ __forceinline__ void stg_dev4(void* p, unsigned int v) {
  asm volatile("global_store_dword %0, %1, off sc1" :: "v"(p), "v"(v));
}
__device__ __forceinline__ bf16x8 asbf(u32x4 v) {
  union { u32x4 u; bf16x8 h; } c; c.u = v; return c.h;
}

#define CLAIMW4(CNTSTR, A, O)                                        \
  asm volatile("s_waitcnt vmcnt(" CNTSTR ")"                         \
    : "+v"((A)[(O)]), "+v"((A)[(O)+1]), "+v"((A)[(O)+2]), "+v"((A)[(O)+3]))

// Zero flags with sc1 stores (MALL-coherent with the scan's sc1 polls;
// hipMemsetAsync's L2-path zeros raced prior-launch sc1 values — round 0).
__global__ void flag_init(unsigned int* __restrict__ flags) {
  stg_dev4(flags + blockIdx.x * 256 + threadIdx.x, 0u);
}

// xtp A-frags (16x16x32 A: m=lane&15, k=kk*32+(lane>>4)*8+j):
// idx = ((t*8+p)*9 + kk)*512 + l*8 + j
__global__ void prepack_kernel(const float* __restrict__ x, const float* __restrict__ mask,
                               const float* __restrict__ ti, __bf16* __restrict__ xtp) {
  int idx = blockIdx.x * 256 + threadIdx.x;        // 18,874,368
  int j = idx & 7, l = (idx >> 3) & 63;
  int rest = idx >> 9;
  int kk = rest % 9;
  int rest2 = rest / 9;
  int p = rest2 & 7;
  int t = rest2 >> 3;
  int b = p * MG + (l & 15);
  int k = kk * 32 + ((l >> 4) << 3) + j;
  float v;
  if (k < 128)       v = x[(b * SS + t) * DD + k];
  else if (k < 256)  v = mask[(b * SS + t) * DD + (k - 128)];
  else if (k == 256) v = ti[b * SS + t];
  else               v = 0.f;
  xtp[idx] = (__bf16)v;
}

// W_ih B-frags per col-slice q: [q][nt][kk][lane][8], nt = gate
__global__ void wih_prepack(const float* __restrict__ W_ih, __bf16* __restrict__ wihp) {
  int idx = blockIdx.x * 256 + threadIdx.x;        // 1,179,648
  int j = idx & 7, l = (idx >> 3) & 63;
  int rest = idx >> 9;
  int kk = rest % 9;
  int rest2 = rest / 9;
  int nt = rest2 & 3, q = rest2 >> 2;
  int col = nt * HH + q * 16 + (l & 15);
  int k = kk * 32 + ((l >> 4) << 3) + j;
  wihp[idx] = (k < IIN) ? (__bf16)W_ih[col * IIN + k] : (__bf16)0.f;
}

__device__ __forceinline__ float sigmoid_f(float v) { return 1.f / (1.f + __expf(-v)); }
__device__ __forceinline__ float tanh_f(float v)    { return 1.f - 2.f / (__expf(2.f * v) + 1.f); }

__launch_bounds__(256, 2)
__global__ void lstm_scan(const float* __restrict__ W_hh,
                          const float* __restrict__ b_ih, const float* __restrict__ b_hh,
                          const __bf16* __restrict__ xtp, const __bf16* __restrict__ wihp,
                          __bf16* __restrict__ hbuf,
                          float* __restrict__ hlast, unsigned int* __restrict__ flags) {
  // DOUBLE-BUFFERED conflict-free reduce buffer (64 KB, 2 blocks/CU on
  // 160 KB LDS). slot(w,g,r,qh,n16) = (((w*4+g)*4+r)*4+qh)*32 + n16*2+(qh&1)
  // -> bank = 2*n16+(qh&1), 2-way (free). Buffer t&1 is written at deposit(t),
  // read at gate(t), rewritten at t+2 — by then every wave passed the
  // deposit->gate barrier of t+1, so no pre-deposit WAR barrier is needed.
  __shared__ float red_lds[2][8192];

  const int tid = threadIdx.x;
  const int bid = blockIdx.x;
  const int p = bid & 7;                       // batch group == XCD (bid%8)
  const int q = bid >> 3;                      // col slice within group [0,64)
  const int j0 = q * 16;                       // owned h-cols [j0, j0+16)

  const int w = tid >> 6, l = tid & 63;        // wave = K-quarter
  const int n16 = l & 15, qh = l >> 4;
  unsigned int* gflags = flags + p * 256;      // 64 blocks x 4 wave-flags

  // ---- W_hh B-fragments persistent in VGPRs: [nt][i], kk = w*8+i ----
  bf16x8 breg[4][8];
  #pragma unroll
  for (int ntI = 0; ntI < 4; ++ntI) {
    const float* wrow = W_hh + (size_t)(ntI * HH + j0 + n16) * HH;
    #pragma unroll
    for (int i = 0; i < 8; ++i) {
      const float* src = wrow + (w * 8 + i) * 32 + qh * 8;
      bf16x8 bv;
      #pragma unroll
      for (int jj = 0; jj < 8; ++jj) bv[jj] = (__bf16)src[jj];
      breg[ntI][i] = bv;
    }
  }

  // gate-phase cell ownership: this thread owns (row = qh*4 + w, col = j0+n16)
  const int grow = qh * 4 + w;
  float bias_r[4];
  #pragma unroll
  for (int g = 0; g < 4; ++g)
    bias_r[g] = b_ih[g * HH + j0 + n16] + b_hh[g * HH + j0 + n16];
  float creg = 0.f;

  // x-part K split over waves: kk in [xs, xe)
  const int xs = (w == 0) ? 0 : (2 * w + 1);
  const int xe = xs + ((w == 0) ? 3 : 2);

  for (int t = 0; t < SS; ++t) {
    const int rb = t & 1, wb = rb ^ 1;
    float* red = red_lds[t & 1];
    f32x4 acc[4];
    #pragma unroll
    for (int ntI = 0; ntI < 4; ++ntI) acc[ntI] = (f32x4){0.f, 0.f, 0.f, 0.f};

    // x-part (this wave's K-slice), pre-poll; A from xtp, B from wihp (cached)
    for (int kk = xs; kk < xe; ++kk) {
      const __bf16* xb = xtp + ((size_t)(t * 8 + p) * KK_X + kk) * 512 + l * 8;
      bf16x8 a = *(const bf16x8*)xb;
      #pragma unroll
      for (int ntI = 0; ntI < 4; ++ntI) {
        bf16x8 b = *(const bf16x8*)(wihp + ((size_t)(q * 4 + ntI) * KK_X + kk) * 512 + l * 8);
        acc[ntI] = __builtin_amdgcn_mfma_f32_16x16x32_bf16(a, b, acc[ntI], 0, 0, 0);
      }
    }

    // ---- per-wave poll + h-part. Wave w consumes h-cols [256w, 256w+256) ==
    // blocks q' in [16w,16w+16) == flags gflags[64w + lane] (1 dword/lane).
    // Union over the 4 waves covers all 256 flags before the deposit barrier:
    // any producer's flag t certifies its block passed barrier(t-1), i.e. all
    // its waves finished reading slab wb at t-1 -> our gate(t) write is safe.
    // t==0: h0==0 -> skip h-part (hbuf never read before flag-protected
    // write; no hbuf init needed).
    if (t > 0) {
      {
        const unsigned int tgt = (unsigned int)t;
        const unsigned int* fp = gflags + (w << 6) + l;
        for (;;) {
          unsigned int f;
          asm volatile("global_load_dword %0, %1, off sc1\n\t"
                       "s_waitcnt vmcnt(0)"
                       : "=v"(f) : "v"(fp));
          // legit values during poll-t: {t-1, t, t+1} (skew bound <= 1 step);
          // accept only f-t<=1 so stale cross-launch values never unlock.
          if (!__ballot((f - tgt) > 1u)) break;
          __builtin_amdgcn_s_sleep(1);
        }
        __builtin_amdgcn_sched_barrier(0);
      }

      // h-part: this wave's K-quarter (8 ksteps). A via sc1 from MALL, B VGPRs.
      const __bf16* hbL = hbuf + (p * 2 + rb) * HBUF_SLAB + (w * 8) * 512 + l * 8;
      u32x4 A[8];
      #pragma unroll
      for (int i = 0; i < 8; ++i) A[i] = ldg_dev16(hbL + i * 512);

      CLAIMW4("4", A, 0);
      #pragma unroll
      for (int i = 0; i < 4; ++i)
        #pragma unroll
        for (int ntI = 0; ntI < 4; ++ntI)
          acc[ntI] = __builtin_amdgcn_mfma_f32_16x16x32_bf16(asbf(A[i]), breg[ntI][i], acc[ntI], 0, 0, 0);
      CLAIMW4("0", A, 4);
      #pragma unroll
      for (int i = 4; i < 8; ++i)
        #pragma unroll
        for (int ntI = 0; ntI < 4; ++ntI)
          acc[ntI] = __builtin_amdgcn_mfma_f32_16x16x32_bf16(asbf(A[i]), breg[ntI][i], acc[ntI], 0, 0, 0);
    }

    // ---- deposit K-partials into buf[t&1] (no pre-barrier needed: dbuf) ----
    #pragma unroll
    for (int g = 0; g < 4; ++g)
      #pragma unroll
      for (int r = 0; r < 4; ++r)
        red[(((w * 4 + g) * 4 + r) * 4 + qh) * 32 + n16 * 2 + (qh & 1)] = acc[g][r];
    __syncthreads();   // the ONE barrier/step: deposit -> gate

    // ---- gate phase: own cell (grow, j0+n16); own partial from register ----
    {
      __bf16* hw = hbuf + (p * 2 + wb) * HBUF_SLAB;
      float gv[4];
      #pragma unroll
      for (int g = 0; g < 4; ++g) {
        // own wave's partial for r = w (wave-uniform select)
        float own = (w == 0) ? acc[g][0] : (w == 1) ? acc[g][1]
                  : (w == 2) ? acc[g][2] : acc[g][3];
        float s = own + bias_r[g];
        #pragma unroll
        for (int wo = 0; wo < 4; ++wo)
          if (wo != w)   // w wave-uniform: 3 reads survive per wave
            s += red[(((wo * 4 + g) * 4 + w) * 4 + qh) * 32 + n16 * 2 + (qh & 1)];
        gv[g] = s;
      }
      float i_ = sigmoid_f(gv[0]);
      float f_ = sigmoid_f(gv[1]);
      float g_ = tanh_f(gv[2]);
      float o_ = sigmoid_f(gv[3]);
      float c  = f_ * creg + i_ * g_;
      creg = c;
      float h  = o_ * tanh_f(c);

      // pack 2 adjacent cols via shfl, even lanes store one dword
      union { __bf16 b; unsigned short u; } cv; cv.b = (__bf16)h;
      unsigned int hu = (unsigned int)cv.u;
      unsigned int partner = __shfl_xor(hu, 1);
      if ((n16 & 1) == 0) {
        unsigned int dw = hu | (partner << 16);
        int k = j0 + n16;
        int kk = k >> 5, q2 = (k >> 3) & 3, jj = k & 7;
        stg_dev4(hw + kk * 512 + (q2 * 16 + grow) * 8 + jj, dw);
      }
      if (t == SS - 1) hlast[(p * MG + grow) * HH + j0 + n16] = h;
    }

    // ---- per-wave signal: drain own wave's sc1 stores (release ordering on
    // the MALL-coherent stream), then lane0 releases the wave-flag ----
    asm volatile("s_waitcnt vmcnt(0)" ::: "memory");
    if (t < SS - 1 && l == 0) {
      stg_dev4(gflags + q * 4 + w, (unsigned int)(t + 1));
    }
  }
}

__global__ void fc_kernel(const float* __restrict__ hlast, const float* __restrict__ W_fc,
                          const float* __restrict__ b_fc, float* __restrict__ out) {
  int b = blockIdx.x;            // 128
  int t = threadIdx.x;           // 256
  int o = t >> 2, part = t & 3;
  const float* hr = hlast + b * HH;
  const float* wr = W_fc + o * HH;
  float s = 0.f;
  #pragma unroll 4
  for (int k0 = part * 4; k0 < HH; k0 += 16) {
    float4 hv = *(const float4*)(hr + k0);
    float4 wv = *(const float4*)(wr + k0);
    s += hv.x * wv.x + hv.y * wv.y + hv.z * wv.z + hv.w * wv.w;
  }
  s += __shfl_xor(s, 1);
  s += __shfl_xor(s, 2);
  if (part == 0) out[b * OO + o] = s + b_fc[o];
}

extern "C" void kernel_launch(void* const* d_in, const int* in_sizes, int n_in,
                              void* d_out, int out_size, void* d_ws, size_t ws_size,
                              hipStream_t stream) {
  const float* x    = (const float*)d_in[0];
  const float* mask = (const float*)d_in[1];
  const float* ti   = (const float*)d_in[2];
  const float* W_ih = (const float*)d_in[3];
  const float* W_hh = (const float*)d_in[4];
  const float* b_ih = (const float*)d_in[5];
  const float* b_hh = (const float*)d_in[6];
  const float* W_fc = (const float*)d_in[7];
  const float* b_fc = (const float*)d_in[8];
  float* out = (float*)d_out;

  char* ws = (char*)d_ws;
  unsigned int* flags = (unsigned int*)ws;
  __bf16* hbuf  = (__bf16*)(ws + WS_HBUF);
  float*  hlast = (float*)(ws + WS_HLAST);
  __bf16* xtp   = (__bf16*)(ws + WS_XTP);
  __bf16* wihp  = (__bf16*)(ws + WS_WIHP);

  // zero flags with sc1 stores (MALL-coherent with the scan kernel's polls);
  // hbuf needs no init: t=0 skips the h-part.
  flag_init<<<8, 256, 0, stream>>>(flags);

  prepack_kernel<<<(SS * NGROUP * XTP_TP) / 256, 256, 0, stream>>>(x, mask, ti, xtp);
  wih_prepack<<<(GBLK * WIH_BLK) / 256, 256, 0, stream>>>(W_ih, wihp);
  lstm_scan<<<NGROUP * GBLK, 256, 0, stream>>>(W_hh, b_ih, b_hh, xtp, wihp, hbuf, hlast, flags);
  fc_kernel<<<BB, 256, 0, stream>>>(hlast, W_fc, b_fc, out);
}